// Round 1
// baseline (146.480 us; speedup 1.0000x reference)
//
#include <hip/hip_runtime.h>

// MWPT: 3-level wavelet packet, KS=8, circular pad(3,3), stride-2.
// y[n] = sum_k x[(2n+k-3) mod T] * w[k];  hi[j] = (-1)^j * ker[7-j]
//
// Output layout (flat, fp32):
//   level1 [128][2][32768]  @ 0          order [a0, a4]
//   level2 [128][4][16384]  @ 8388608    order [b0, b2, b6, b4]
//   level3 [128][8][8192]   @ 16777216   order [c0, c1, c3, c2, c6, c7, c5, c4]

#define T_LEN   65536
#define T_MASK  65535
#define HALO_L  21
#define CHUNK   2048                        // x samples per block
#define LOAD_N  (CHUNK + 48)                // +21 left, +27 right halo = 2096
#define PADIDX(i) ((i) + ((i) >> 3))        // pad 1 float per 8 -> lane stride 9, conflict-free

__global__ __launch_bounds__(256) void mwpt_kernel(
    const float* __restrict__ x, const float* __restrict__ ker,
    float* __restrict__ out)
{
    __shared__ float xl[PADIDX(LOAD_N - 1) + 1];   // 2356 floats ~ 9.4 KB

    const int t   = threadIdx.x;
    const int seg = blockIdx.x;       // 0..31
    const int bi  = blockIdx.y;       // 0..127
    const int base = seg * CHUNK;
    const float* __restrict__ xrow = x + (size_t)bi * T_LEN;

    // stage chunk + halo, circular wrap handled here once
    for (int i = t; i < LOAD_N; i += 256) {
        int g = (base + i - HALO_L) & T_MASK;
        xl[PADIDX(i)] = xrow[g];
    }

    // QMF pair
    float lo[8], hi[8];
#pragma unroll
    for (int j = 0; j < 8; ++j) lo[j] = ker[j];
#pragma unroll
    for (int j = 0; j < 8; ++j) hi[j] = (j & 1) ? -ker[7 - j] : ker[7 - j];

    __syncthreads();

    // x window for this thread: local sample 8t + j, j = 0..49
    float xw[50];
    const int wbase = 9 * t;          // PADIDX(8t) = 9t
#pragma unroll
    for (int j = 0; j < 50; ++j) xw[j] = xl[wbase + j + (j >> 3)];

    // level 1: a(r1 = 4t-9+i), i = 0..21; taps hit xw[2i + k]
    float a0v[22], a4v[22];
#pragma unroll
    for (int i = 0; i < 22; ++i) {
        float s0 = 0.f, s4 = 0.f;
#pragma unroll
        for (int k = 0; k < 8; ++k) {
            float xv = xw[2 * i + k];
            s0 += xv * lo[k];
            s4 += xv * hi[k];
        }
        a0v[i] = s0; a4v[i] = s4;
    }

    // level 2: b(r2 = 2t-3+j), j = 0..7; taps hit a[2j + k]
    float b0v[8], b2v[8], b4v[8], b6v[8];
#pragma unroll
    for (int j = 0; j < 8; ++j) {
        float s0 = 0.f, s2 = 0.f, s4 = 0.f, s6 = 0.f;
#pragma unroll
        for (int k = 0; k < 8; ++k) {
            float v0 = a0v[2 * j + k], v4 = a4v[2 * j + k];
            s0 += v0 * lo[k]; s2 += v0 * hi[k];
            s4 += v4 * lo[k]; s6 += v4 * hi[k];
        }
        b0v[j] = s0; b2v[j] = s2; b4v[j] = s4; b6v[j] = s6;
    }

    // level 3: c(n3 = this thread); taps hit b[k]
    float c[8] = {0, 0, 0, 0, 0, 0, 0, 0};
#pragma unroll
    for (int k = 0; k < 8; ++k) {
        c[0] += b0v[k] * lo[k]; c[1] += b0v[k] * hi[k];
        c[2] += b2v[k] * lo[k]; c[3] += b2v[k] * hi[k];
        c[4] += b4v[k] * lo[k]; c[5] += b4v[k] * hi[k];
        c[6] += b6v[k] * lo[k]; c[7] += b6v[k] * hi[k];
    }

    const int n3 = seg * 256 + t;     // 0..8191

    // level 1: this thread owns n1 = 4*n3 .. 4*n3+3  -> local i = 9..12
    {
        size_t o = (size_t)bi * 65536 + 4 * (size_t)n3;
        *(float4*)(out + o)         = make_float4(a0v[9], a0v[10], a0v[11], a0v[12]);
        *(float4*)(out + o + 32768) = make_float4(a4v[9], a4v[10], a4v[11], a4v[12]);
    }
    // level 2: this thread owns n2 = 2*n3, 2*n3+1 -> local j = 3, 4; order [b0,b2,b6,b4]
    {
        size_t o = 8388608ull + (size_t)bi * 65536 + 2 * (size_t)n3;
        *(float2*)(out + o)             = make_float2(b0v[3], b0v[4]);
        *(float2*)(out + o + 16384)     = make_float2(b2v[3], b2v[4]);
        *(float2*)(out + o + 2 * 16384) = make_float2(b6v[3], b6v[4]);
        *(float2*)(out + o + 3 * 16384) = make_float2(b4v[3], b4v[4]);
    }
    // level 3: order [c0, c1, c3, c2, c6, c7, c5, c4]
    {
        size_t o = 16777216ull + (size_t)bi * 65536 + (size_t)n3;
        out[o]            = c[0];
        out[o + 8192]     = c[1];
        out[o + 2 * 8192] = c[3];
        out[o + 3 * 8192] = c[2];
        out[o + 4 * 8192] = c[6];
        out[o + 5 * 8192] = c[7];
        out[o + 6 * 8192] = c[5];
        out[o + 7 * 8192] = c[4];
    }
}

extern "C" void kernel_launch(void* const* d_in, const int* in_sizes, int n_in,
                              void* d_out, int out_size, void* d_ws, size_t ws_size,
                              hipStream_t stream) {
    const float* x   = (const float*)d_in[0];
    const float* ker = (const float*)d_in[1];
    float* out = (float*)d_out;
    dim3 grid(32, 128), block(256);
    hipLaunchKernelGGL(mwpt_kernel, grid, block, 0, stream, x, ker, out);
}

// Round 2
// 131.018 us; speedup vs baseline: 1.1180x; 1.1180x over previous
//
#include <hip/hip_runtime.h>

// MWPT: 3-level wavelet packet, KS=8, circular pad(3,3), stride-2.
// y[n] = sum_k x[(2n+k-3) mod T] * w[k];  hi[j] = (-1)^j * ker[7-j]
//
// Level-by-level through LDS (low register pressure, no cone recomputation):
//   stage x chunk+halo -> a0/a4 (LDS+global) -> b0..b6 (LDS+global, reuses xs
//   region) -> c0..c7 (global).
//
// Output layout (flat, fp32):
//   level1 [128][2][32768]  @ 0          order [a0, a4]
//   level2 [128][4][16384]  @ 8388608    order [b0, b2, b6, b4]
//   level3 [128][8][8192]   @ 16777216   order [c0, c1, c3, c2, c6, c7, c5, c4]

#define T_MASK  65535
#define PAD(i)  ((i) + ((i) >> 3))   // +1 float per 8: stride-8/4/2 reads <= 2-way

#define XS_N 2090                    // x local  [0,2089] <-> x[(2N1-21+i) mod T]
#define AS_N 1042                    // a local  [0,1041] <-> a[N1-9+j]
#define BS_N 518                     // b local  [0, 517] <-> b[N2-3+m]
#define XS_P (PAD(XS_N - 1) + 1)     // 2351
#define AS_P (PAD(AS_N - 1) + 1)     // 1172
#define BS_P (PAD(BS_N - 1) + 1)     // 582  (4*582 = 2328 <= XS_P, fits in xs)

__global__ __launch_bounds__(256) void mwpt_kernel(
    const float* __restrict__ x, const float* __restrict__ ker,
    float* __restrict__ out)
{
    __shared__ float lds[XS_P + 2 * AS_P];   // 4695 floats = 18.8 KB
    float* xs  = lds;                         // reused for bs after level 1
    float* as0 = lds + XS_P;
    float* as1 = lds + XS_P + AS_P;
    float* bs0 = lds;                         // b0
    float* bs1 = lds + BS_P;                  // b2
    float* bs2 = lds + 2 * BS_P;              // b4
    float* bs3 = lds + 3 * BS_P;              // b6

    const int t   = threadIdx.x;
    const int seg = blockIdx.x;               // 0..31
    const int bi  = blockIdx.y;               // 0..127
    const int N3  = seg * 256;
    const int N2  = seg * 512;
    const int N1  = seg * 1024;
    const float* __restrict__ xrow = x + (size_t)bi * 65536;

    // ---- stage x (chunk + halo), circular wrap once ----
    const int xg0 = 2 * N1 - 21;
    for (int i = t; i < XS_N; i += 256)
        xs[PAD(i)] = xrow[(xg0 + i) & T_MASK];

    float lo[8], hi[8];
#pragma unroll
    for (int k = 0; k < 8; ++k) lo[k] = ker[k];
#pragma unroll
    for (int k = 0; k < 8; ++k) hi[k] = (k & 1) ? -ker[7 - k] : ker[7 - k];

    __syncthreads();

    // ---- level 1: a[j] = sum_k xs[2j+k]*w.  main: j = 4t+9 .. 4t+12 ----
    {
        const int j0 = 4 * t + 9;
        float xv[14];
#pragma unroll
        for (int q = 0; q < 14; ++q) xv[q] = xs[PAD(2 * j0 + q)];
        float r0[4], r4[4];
#pragma unroll
        for (int i = 0; i < 4; ++i) {
            float s0 = 0.f, s4 = 0.f;
#pragma unroll
            for (int k = 0; k < 8; ++k) {
                float v = xv[2 * i + k];
                s0 += v * lo[k]; s4 += v * hi[k];
            }
            r0[i] = s0; r4[i] = s4;
        }
#pragma unroll
        for (int i = 0; i < 4; ++i) {
            as0[PAD(j0 + i)] = r0[i];
            as1[PAD(j0 + i)] = r4[i];
        }
        if (t < 18) {  // halo j in [0,8] u [1033,1041]
            int j = (t < 9) ? t : (1024 + t);
            float s0 = 0.f, s4 = 0.f;
#pragma unroll
            for (int k = 0; k < 8; ++k) {
                float v = xs[PAD(2 * j + k)];
                s0 += v * lo[k]; s4 += v * hi[k];
            }
            as0[PAD(j)] = s0; as1[PAD(j)] = s4;
        }
        // global: n1 = N1 + 4t + i  (j = n1 + 9 - N1local)
        size_t o = (size_t)bi * 65536 + (size_t)N1 + 4 * (size_t)t;
        *(float4*)(out + o)         = make_float4(r0[0], r0[1], r0[2], r0[3]);
        *(float4*)(out + o + 32768) = make_float4(r4[0], r4[1], r4[2], r4[3]);
    }

    __syncthreads();

    // ---- level 2: b[m] = sum_k as[2m+k]*w.  main: m = 2t+3, 2t+4 ----
    // bs writes go to the (now dead) xs region; as region untouched.
    {
        const int m0 = 2 * t + 3;
        float av0[10], av1[10];
#pragma unroll
        for (int q = 0; q < 10; ++q) {
            av0[q] = as0[PAD(2 * m0 + q)];
            av1[q] = as1[PAD(2 * m0 + q)];
        }
        float v0[2], v2[2], v4[2], v6[2];
#pragma unroll
        for (int j = 0; j < 2; ++j) {
            float s0 = 0.f, s2 = 0.f, s4 = 0.f, s6 = 0.f;
#pragma unroll
            for (int k = 0; k < 8; ++k) {
                float a0 = av0[2 * j + k], a4 = av1[2 * j + k];
                s0 += a0 * lo[k]; s2 += a0 * hi[k];
                s4 += a4 * lo[k]; s6 += a4 * hi[k];
            }
            v0[j] = s0; v2[j] = s2; v4[j] = s4; v6[j] = s6;
        }
#pragma unroll
        for (int j = 0; j < 2; ++j) {
            bs0[PAD(m0 + j)] = v0[j];
            bs1[PAD(m0 + j)] = v2[j];
            bs2[PAD(m0 + j)] = v4[j];
            bs3[PAD(m0 + j)] = v6[j];
        }
        if (t < 6) {  // halo m in {0,1,2,515,516,517}
            int m = (t < 3) ? t : (512 + t);
            float s0 = 0.f, s2 = 0.f, s4 = 0.f, s6 = 0.f;
#pragma unroll
            for (int k = 0; k < 8; ++k) {
                float a0 = as0[PAD(2 * m + k)], a4 = as1[PAD(2 * m + k)];
                s0 += a0 * lo[k]; s2 += a0 * hi[k];
                s4 += a4 * lo[k]; s6 += a4 * hi[k];
            }
            bs0[PAD(m)] = s0; bs1[PAD(m)] = s2;
            bs2[PAD(m)] = s4; bs3[PAD(m)] = s6;
        }
        // global: order [b0, b2, b6, b4]; n2 = N2 + 2t + j
        size_t o = 8388608ull + (size_t)bi * 65536 + (size_t)N2 + 2 * (size_t)t;
        *(float2*)(out + o)             = make_float2(v0[0], v0[1]);
        *(float2*)(out + o + 16384)     = make_float2(v2[0], v2[1]);
        *(float2*)(out + o + 2 * 16384) = make_float2(v6[0], v6[1]);
        *(float2*)(out + o + 3 * 16384) = make_float2(v4[0], v4[1]);
    }

    __syncthreads();

    // ---- level 3: c[n3=N3+t] = sum_k bs[2t+k]*w ----
    {
        float c0 = 0.f, c1 = 0.f, c2 = 0.f, c3 = 0.f;
        float c4 = 0.f, c5 = 0.f, c6 = 0.f, c7 = 0.f;
#pragma unroll
        for (int k = 0; k < 8; ++k) {
            float b0 = bs0[PAD(2 * t + k)];
            float b2 = bs1[PAD(2 * t + k)];
            float b4 = bs2[PAD(2 * t + k)];
            float b6 = bs3[PAD(2 * t + k)];
            c0 += b0 * lo[k]; c1 += b0 * hi[k];
            c2 += b2 * lo[k]; c3 += b2 * hi[k];
            c4 += b4 * lo[k]; c5 += b4 * hi[k];
            c6 += b6 * lo[k]; c7 += b6 * hi[k];
        }
        // global: order [c0, c1, c3, c2, c6, c7, c5, c4]
        size_t o = 16777216ull + (size_t)bi * 65536 + (size_t)N3 + (size_t)t;
        out[o]            = c0;
        out[o + 8192]     = c1;
        out[o + 2 * 8192] = c3;
        out[o + 3 * 8192] = c2;
        out[o + 4 * 8192] = c6;
        out[o + 5 * 8192] = c7;
        out[o + 6 * 8192] = c5;
        out[o + 7 * 8192] = c4;
    }
}

extern "C" void kernel_launch(void* const* d_in, const int* in_sizes, int n_in,
                              void* d_out, int out_size, void* d_ws, size_t ws_size,
                              hipStream_t stream) {
    const float* x   = (const float*)d_in[0];
    const float* ker = (const float*)d_in[1];
    float* out = (float*)d_out;
    dim3 grid(32, 128), block(256);
    hipLaunchKernelGGL(mwpt_kernel, grid, block, 0, stream, x, ker, out);
}

// Round 3
// 129.747 us; speedup vs baseline: 1.1290x; 1.0098x over previous
//
#include <hip/hip_runtime.h>

// MWPT: 3-level wavelet packet, KS=8, circular pad(3,3), stride-2.
// y[n] = sum_k x[(2n+k-3) mod T] * w[k];  hi[j] = (-1)^j * ker[7-j]
//
// CHUNK = 4096 x-samples per block, level-by-level through LDS.
// Each thread: 8 L1 outputs (2x float4), 4 L2 (float4), 2 L3 (float2).
// Staging: wrap-safe aligned float4 global loads.
// LDS pad: +1 float per 16 -> L1 window read (raw stride 16) becomes
// stride 17, gcd(17,32)=1 -> <=2-way (free). Other strides <=3-way.
//
// Output layout (flat, fp32):
//   level1 [128][2][32768]  @ 0          order [a0, a4]
//   level2 [128][4][16384]  @ 8388608    order [b0, b2, b6, b4]
//   level3 [128][8][8192]   @ 16777216   order [c0, c1, c3, c2, c6, c7, c5, c4]

#define T_MASK 65535
#define P(i)   ((i) + ((i) >> 4))

#define XS_N 4144                 // x local i <-> x[(A + i) mod T], A = 4096*seg - 24
#define AS_N 2066                 // a local jj <-> a[N1 - 9 + jj]
#define BS_N 1030                 // b local m  <-> b[N2 - 3 + m]
#define XS_P (P(XS_N - 1) + 1)    // 4402
#define AS_P (P(AS_N - 1) + 1)    // 2195
#define BS_P (P(BS_N - 1) + 1)    // 1094 ; 4*1094 = 4376 <= XS_P (reuse)

__global__ __launch_bounds__(256) void mwpt_kernel(
    const float* __restrict__ x, const float* __restrict__ ker,
    float* __restrict__ out)
{
    __shared__ float lds[XS_P + 2 * AS_P];    // 8792 floats = 35.2 KB
    float* xs  = lds;
    float* as0 = lds + XS_P;
    float* as1 = lds + XS_P + AS_P;
    float* bs0 = lds;                          // xs region reused after L1
    float* bs1 = lds + BS_P;
    float* bs2 = lds + 2 * BS_P;
    float* bs3 = lds + 3 * BS_P;

    const int t   = threadIdx.x;
    const int seg = blockIdx.x;                // 0..15
    const int bi  = blockIdx.y;                // 0..127
    const int N1  = seg * 2048;
    const int N2  = seg * 1024;
    const int N3  = seg * 512;
    const float* __restrict__ xrow = x + (size_t)bi * 65536;

    // ---- stage x: 1036 aligned float4 loads (wrap-safe: A%4==0, no cross) ----
    const int A = 4096 * seg - 24;
    for (int u = t; u < 1036; u += 256) {
        int g = (A + 4 * u) & T_MASK;
        float4 v = *(const float4*)(xrow + g);
        int ip = P(4 * u);                     // 4u%16 in {0,4,8,12}: contiguous
        xs[ip] = v.x; xs[ip + 1] = v.y; xs[ip + 2] = v.z; xs[ip + 3] = v.w;
    }

    float lo[8], hi[8];
#pragma unroll
    for (int k = 0; k < 8; ++k) lo[k] = ker[k];
#pragma unroll
    for (int k = 0; k < 8; ++k) hi[k] = (k & 1) ? -ker[7 - k] : ker[7 - k];

    __syncthreads();

    // ---- level 1: a[jj] = sum_k xs[2*jj + 3 + k] * w ; main jj = 8t+9..8t+16 ----
    {
        float xv[22];
#pragma unroll
        for (int q = 0; q < 22; ++q) xv[q] = xs[P(16 * t + 21 + q)];
        float r0[8], r4[8];
#pragma unroll
        for (int i = 0; i < 8; ++i) {
            float s0 = 0.f, s4 = 0.f;
#pragma unroll
            for (int k = 0; k < 8; ++k) {
                float v = xv[2 * i + k];
                s0 += v * lo[k]; s4 += v * hi[k];
            }
            r0[i] = s0; r4[i] = s4;
        }
#pragma unroll
        for (int i = 0; i < 8; ++i) {
            as0[P(8 * t + 9 + i)] = r0[i];
            as1[P(8 * t + 9 + i)] = r4[i];
        }
        if (t < 18) {                          // halo jj in [0,8] u [2057,2065]
            int jj = (t < 9) ? t : (2048 + t);
            float s0 = 0.f, s4 = 0.f;
#pragma unroll
            for (int k = 0; k < 8; ++k) {
                float v = xs[P(2 * jj + 3 + k)];
                s0 += v * lo[k]; s4 += v * hi[k];
            }
            as0[P(jj)] = s0; as1[P(jj)] = s4;
        }
        size_t o = (size_t)bi * 65536 + (size_t)N1 + 8 * (size_t)t;
        *(float4*)(out + o)             = make_float4(r0[0], r0[1], r0[2], r0[3]);
        *(float4*)(out + o + 4)         = make_float4(r0[4], r0[5], r0[6], r0[7]);
        *(float4*)(out + o + 32768)     = make_float4(r4[0], r4[1], r4[2], r4[3]);
        *(float4*)(out + o + 32768 + 4) = make_float4(r4[4], r4[5], r4[6], r4[7]);
    }

    __syncthreads();

    // ---- level 2: b[m] = sum_k as[2m + k] * w ; main m = 4t+3..4t+6 ----
    {
        float av0[14], av1[14];
#pragma unroll
        for (int q = 0; q < 14; ++q) {
            av0[q] = as0[P(8 * t + 6 + q)];
            av1[q] = as1[P(8 * t + 6 + q)];
        }
        float v0[4], v2[4], v4[4], v6[4];
#pragma unroll
        for (int i = 0; i < 4; ++i) {
            float s0 = 0.f, s2 = 0.f, s4 = 0.f, s6 = 0.f;
#pragma unroll
            for (int k = 0; k < 8; ++k) {
                float a0 = av0[2 * i + k], a4 = av1[2 * i + k];
                s0 += a0 * lo[k]; s2 += a0 * hi[k];
                s4 += a4 * lo[k]; s6 += a4 * hi[k];
            }
            v0[i] = s0; v2[i] = s2; v4[i] = s4; v6[i] = s6;
        }
#pragma unroll
        for (int i = 0; i < 4; ++i) {
            int m = 4 * t + 3 + i;
            bs0[P(m)] = v0[i]; bs1[P(m)] = v2[i];
            bs2[P(m)] = v4[i]; bs3[P(m)] = v6[i];
        }
        if (t < 6) {                           // halo m in [0,2] u [1027,1029]
            int m = (t < 3) ? t : (1024 + t);
            float s0 = 0.f, s2 = 0.f, s4 = 0.f, s6 = 0.f;
#pragma unroll
            for (int k = 0; k < 8; ++k) {
                float a0 = as0[P(2 * m + k)], a4 = as1[P(2 * m + k)];
                s0 += a0 * lo[k]; s2 += a0 * hi[k];
                s4 += a4 * lo[k]; s6 += a4 * hi[k];
            }
            bs0[P(m)] = s0; bs1[P(m)] = s2;
            bs2[P(m)] = s4; bs3[P(m)] = s6;
        }
        // order [b0, b2, b6, b4]
        size_t o = 8388608ull + (size_t)bi * 65536 + (size_t)N2 + 4 * (size_t)t;
        *(float4*)(out + o)             = make_float4(v0[0], v0[1], v0[2], v0[3]);
        *(float4*)(out + o + 16384)     = make_float4(v2[0], v2[1], v2[2], v2[3]);
        *(float4*)(out + o + 2 * 16384) = make_float4(v6[0], v6[1], v6[2], v6[3]);
        *(float4*)(out + o + 3 * 16384) = make_float4(v4[0], v4[1], v4[2], v4[3]);
    }

    __syncthreads();

    // ---- level 3: c[n3] = sum_k bs[2(n3-N3) + k] * w ; n3 = N3 + 2t + {0,1} ----
    {
        float bv0[10], bv1[10], bv2[10], bv3[10];
#pragma unroll
        for (int q = 0; q < 10; ++q) {
            bv0[q] = bs0[P(4 * t + q)];
            bv1[q] = bs1[P(4 * t + q)];
            bv2[q] = bs2[P(4 * t + q)];
            bv3[q] = bs3[P(4 * t + q)];
        }
        float c0[2], c1[2], c2[2], c3[2], c4[2], c5[2], c6[2], c7[2];
#pragma unroll
        for (int j = 0; j < 2; ++j) {
            float s0 = 0.f, s1 = 0.f, s2 = 0.f, s3 = 0.f;
            float s4 = 0.f, s5 = 0.f, s6 = 0.f, s7 = 0.f;
#pragma unroll
            for (int k = 0; k < 8; ++k) {
                float b0 = bv0[2 * j + k], b2 = bv1[2 * j + k];
                float b4 = bv2[2 * j + k], b6 = bv3[2 * j + k];
                s0 += b0 * lo[k]; s1 += b0 * hi[k];
                s2 += b2 * lo[k]; s3 += b2 * hi[k];
                s4 += b4 * lo[k]; s5 += b4 * hi[k];
                s6 += b6 * lo[k]; s7 += b6 * hi[k];
            }
            c0[j] = s0; c1[j] = s1; c2[j] = s2; c3[j] = s3;
            c4[j] = s4; c5[j] = s5; c6[j] = s6; c7[j] = s7;
        }
        // order [c0, c1, c3, c2, c6, c7, c5, c4]
        size_t o = 16777216ull + (size_t)bi * 65536 + (size_t)N3 + 2 * (size_t)t;
        *(float2*)(out + o)            = make_float2(c0[0], c0[1]);
        *(float2*)(out + o + 8192)     = make_float2(c1[0], c1[1]);
        *(float2*)(out + o + 2 * 8192) = make_float2(c3[0], c3[1]);
        *(float2*)(out + o + 3 * 8192) = make_float2(c2[0], c2[1]);
        *(float2*)(out + o + 4 * 8192) = make_float2(c6[0], c6[1]);
        *(float2*)(out + o + 5 * 8192) = make_float2(c7[0], c7[1]);
        *(float2*)(out + o + 6 * 8192) = make_float2(c5[0], c5[1]);
        *(float2*)(out + o + 7 * 8192) = make_float2(c4[0], c4[1]);
    }
}

extern "C" void kernel_launch(void* const* d_in, const int* in_sizes, int n_in,
                              void* d_out, int out_size, void* d_ws, size_t ws_size,
                              hipStream_t stream) {
    const float* x   = (const float*)d_in[0];
    const float* ker = (const float*)d_in[1];
    float* out = (float*)d_out;
    dim3 grid(16, 128), block(256);
    hipLaunchKernelGGL(mwpt_kernel, grid, block, 0, stream, x, ker, out);
}